// Round 2
// baseline (1123.778 us; speedup 1.0000x reference)
//
#include <hip/hip_runtime.h>
#include <hip/hip_cooperative_groups.h>
#include <math.h>

namespace cg = cooperative_groups;

#define NODES 10000
#define NEDGE 320000
#define INDIM 512
#define CH    128
#define NB    256
#define NT    256
#define GSIZE (NB * NT)

typedef float f32x4 __attribute__((ext_vector_type(4)));
typedef short s16x8 __attribute__((ext_vector_type(8)));
typedef short s16x4 __attribute__((ext_vector_type(4)));

// bf16 round-to-nearest-even
__device__ __forceinline__ short f2bf(float f) {
    unsigned u = __float_as_uint(f);
    return (short)((u + 0x7fffu + ((u >> 16) & 1u)) >> 16);
}
__device__ __forceinline__ float bf2f(short s) {
    return __uint_as_float(((unsigned)(unsigned short)s) << 16);
}

// split-bf16 MFMA GEMM tile: rows [blockIdx.x*64, +64) x 128 cols, out = A@W^T (+bias) (opt l2norm*1.8)
__device__ __forceinline__ void gemm_tile(const float* __restrict__ A, const float* __restrict__ W,
                                          const float* __restrict__ bias, float* __restrict__ outp,
                                          int M, int K, bool l2n,
                                          short* Ah, short* Al, short* Bh, short* Bl) {
    const int SROW = 72;
    int tid = threadIdx.x;
    int row0 = blockIdx.x * 64;
    int wave = tid >> 6, lane = tid & 63, quad = lane >> 4, l16 = lane & 15;

    f32x4 acc[8];
#pragma unroll
    for (int t = 0; t < 8; t++) acc[t] = (f32x4){0.f, 0.f, 0.f, 0.f};

    for (int kb = 0; kb < K; kb += 64) {
        __syncthreads();
#pragma unroll
        for (int i = 0; i < 4; i++) {  // A tile: 64 rows x 64 k
            int idx = tid + NT * i;
            int j = idx & 15, r = idx >> 4;
            float4 v = {0.f, 0.f, 0.f, 0.f};
            int grow = row0 + r;
            if (grow < M) v = *(const float4*)(A + (size_t)grow * K + kb + 4 * j);
            float vv[4] = {v.x, v.y, v.z, v.w};
            s16x4 h4, l4;
#pragma unroll
            for (int q = 0; q < 4; q++) {
                short hs = f2bf(vv[q]);
                h4[q] = hs;
                l4[q] = f2bf(vv[q] - bf2f(hs));
            }
            *(s16x4*)&Ah[r * SROW + 4 * j] = h4;
            *(s16x4*)&Al[r * SROW + 4 * j] = l4;
        }
#pragma unroll
        for (int i = 0; i < 8; i++) {  // B tile: 128 n x 64 k
            int idx = tid + NT * i;
            int j = idx & 15, n = idx >> 4;
            float4 v = *(const float4*)(W + (size_t)n * K + kb + 4 * j);
            float vv[4] = {v.x, v.y, v.z, v.w};
            s16x4 h4, l4;
#pragma unroll
            for (int q = 0; q < 4; q++) {
                short hs = f2bf(vv[q]);
                h4[q] = hs;
                l4[q] = f2bf(vv[q] - bf2f(hs));
            }
            *(s16x4*)&Bh[n * SROW + 4 * j] = h4;
            *(s16x4*)&Bl[n * SROW + 4 * j] = l4;
        }
        __syncthreads();

#pragma unroll
        for (int kk = 0; kk < 64; kk += 32) {
            int aoff = (wave * 16 + l16) * SROW + kk + quad * 8;
            s16x8 ah = *(const s16x8*)&Ah[aoff];
            s16x8 al = *(const s16x8*)&Al[aoff];
#pragma unroll
            for (int t = 0; t < 8; t++) {
                int boff = (t * 16 + l16) * SROW + kk + quad * 8;
                s16x8 bh = *(const s16x8*)&Bh[boff];
                s16x8 bl = *(const s16x8*)&Bl[boff];
                acc[t] = __builtin_amdgcn_mfma_f32_16x16x32_bf16(ah, bh, acc[t], 0, 0, 0);
                acc[t] = __builtin_amdgcn_mfma_f32_16x16x32_bf16(ah, bl, acc[t], 0, 0, 0);
                acc[t] = __builtin_amdgcn_mfma_f32_16x16x32_bf16(al, bh, acc[t], 0, 0, 0);
            }
        }
    }

    if (bias) {
#pragma unroll
        for (int t = 0; t < 8; t++) {
            float bv = bias[t * 16 + l16];
#pragma unroll
            for (int r = 0; r < 4; r++) acc[t][r] += bv;
        }
    }
    if (l2n) {
#pragma unroll
        for (int r = 0; r < 4; r++) {
            float ss = 0.f;
#pragma unroll
            for (int t = 0; t < 8; t++) ss += acc[t][r] * acc[t][r];
#pragma unroll
            for (int off = 1; off < 16; off <<= 1) ss += __shfl_xor(ss, off, 64);
            float scale = 1.8f / fmaxf(sqrtf(ss), 1e-12f);
#pragma unroll
            for (int t = 0; t < 8; t++) acc[t][r] *= scale;
        }
    }
#pragma unroll
    for (int r = 0; r < 4; r++) {
        int grow = row0 + wave * 16 + quad * 4 + r;
        if (grow < M)
#pragma unroll
            for (int t = 0; t < 8; t++)
                outp[(size_t)grow * CH + t * 16 + l16] = acc[t][r];
    }
}

__global__ __launch_bounds__(NT) void fused(
    const float* __restrict__ x, const float* __restrict__ x2, const float* __restrict__ W2,
    const float* __restrict__ b2, const float* __restrict__ Wg, const float* __restrict__ bg,
    const float* __restrict__ W22, const int* __restrict__ ei, float* __restrict__ out,
    int* deg, int* cursor, int* startArr, float* dinv, int2* pairs, int* blockSum,
    float* h, float* xw, float* z1, float* z2v) {
    cg::grid_group grid = cg::this_grid();
    __shared__ __align__(16) char smem[55296];
    short* Ah = (short*)smem;
    short* Al = (short*)(smem + 9216);
    short* Bh = (short*)(smem + 18432);
    short* Bl = (short*)(smem + 36864);
    int* si = (int*)smem;
    float* sred = (float*)smem;

    int tid = threadIdx.x, b = blockIdx.x;
    int gtid = b * NT + tid;
    int lane = tid & 63, wv = tid >> 6;
    int wid = gtid >> 6;  // 0..1023

    // ---- P0: init deg/cursor ----
    for (int i = gtid; i < NODES; i += GSIZE) { deg[i] = 1; cursor[i] = 0; }
    grid.sync();  // S1

    // ---- P1: count in-degrees, then z2 (independent 400MB stream) ----
    for (int e = gtid; e < NEDGE; e += GSIZE) atomicAdd(&deg[ei[NEDGE + e]], 1);
    {
        const float4* w0 = (const float4*)W22;
        const float4* w1 = (const float4*)(W22 + NODES);
        float4 w0r[10], w1r[10];  // W22 held in registers for all rows this block handles
#pragma unroll
        for (int it = 0; it < 10; it++) {
            int j = tid + NT * it;
            bool ok = j < NODES / 4;
            w0r[it] = ok ? w0[j] : (float4){0.f, 0.f, 0.f, 0.f};
            w1r[it] = ok ? w1[j] : (float4){0.f, 0.f, 0.f, 0.f};
        }
        for (int row = b; row < NODES; row += NB) {
            const float4* xr = (const float4*)(x2 + (size_t)row * NODES);
            float s0 = 0.f, s1 = 0.f;
#pragma unroll
            for (int it = 0; it < 10; it++) {
                int j = tid + NT * it;
                if (j < NODES / 4) {
                    float4 v = xr[j];
                    s0 += v.x * w0r[it].x + v.y * w0r[it].y + v.z * w0r[it].z + v.w * w0r[it].w;
                    s1 += v.x * w1r[it].x + v.y * w1r[it].y + v.z * w1r[it].z + v.w * w1r[it].w;
                }
            }
#pragma unroll
            for (int off = 1; off < 64; off <<= 1) {
                s0 += __shfl_xor(s0, off, 64);
                s1 += __shfl_xor(s1, off, 64);
            }
            if (lane == 0) { sred[wv] = s0; sred[4 + wv] = s1; }
            __syncthreads();
            if (tid == 0) {
                float v0 = sred[0] + sred[1] + sred[2] + sred[3];
                float v1 = sred[4] + sred[5] + sred[6] + sred[7];
                float n = sqrtf(v0 * v0 + v1 * v1);
                z2v[row] = 0.8f * v0 / fmaxf(n, 1e-12f);
            }
            __syncthreads();
        }
    }
    grid.sync();  // S2

    // ---- P2: per-block local exclusive scan of edge-counts (40 nodes/block) + dinv ----
    {
        int base = b * 40;
        if (tid < 40) {
            int i = base + tid;
            si[tid] = (i < NODES) ? deg[i] - 1 : 0;
        }
        __syncthreads();
        if (tid == 0) {
            int run = 0;
            for (int k = 0; k < 40; k++) { int tmp = si[k]; si[k] = run; run += tmp; }
            blockSum[b] = run;
        }
        __syncthreads();
        if (tid < 40) {
            int i = base + tid;
            if (i < NODES) { startArr[i] = si[tid]; dinv[i] = rsqrtf((float)deg[i]); }
        }
    }
    grid.sync();  // S3

    // ---- P3: every block redundantly scans the 256 block sums, adds its offset ----
    {
        si[tid] = blockSum[tid];
        __syncthreads();
        for (int off = 1; off < NB; off <<= 1) {
            int v = (tid >= off) ? si[tid - off] : 0;
            __syncthreads();
            si[tid] += v;
            __syncthreads();
        }
        int blockOff = (b == 0) ? 0 : si[b - 1];
        int base = b * 40;
        if (tid < 40) {
            int i = base + tid;
            if (i < NODES) startArr[i] += blockOff;
        }
        if (gtid == 0) startArr[NODES] = NEDGE;
    }
    grid.sync();  // S4

    // ---- P4: CSR fill (store (src, edge_id) pairs) + gemm1 ----
    for (int e = gtid; e < NEDGE; e += GSIZE) {
        int c = ei[NEDGE + e], src = ei[e];
        int pos = atomicAdd(&cursor[c], 1);
        pairs[startArr[c] + pos] = make_int2(src, e);
    }
    if (b < 157) gemm_tile(x, W2, b2, h, NODES, INDIM, true, Ah, Al, Bh, Bl);
    grid.sync();  // S5

    // ---- P5: gemm2 (xw = h @ Wg^T) ----
    if (b < 157) gemm_tile(h, Wg, nullptr, xw, NODES, CH, false, Ah, Al, Bh, Bl);
    grid.sync();  // S6

    // ---- P6: GCN aggregation, one wave per node, CSR pull (2-way unrolled) ----
    for (int c = wid; c < NODES; c += GSIZE / 64) {
        float di = dinv[c];
        float2 v = *(const float2*)(xw + (size_t)c * CH + 2 * lane);
        float ax = v.x * di * di, ay = v.y * di * di;
        int s = startArr[c], e2 = startArr[c + 1];
        int i = s;
        for (; i + 1 < e2; i += 2) {
            int2 p0 = pairs[i], p1 = pairs[i + 1];
            float c0 = dinv[p0.x] * di, c1 = dinv[p1.x] * di;
            float2 u0 = *(const float2*)(xw + (size_t)p0.x * CH + 2 * lane);
            float2 u1 = *(const float2*)(xw + (size_t)p1.x * CH + 2 * lane);
            ax += u0.x * c0 + u1.x * c1;
            ay += u0.y * c0 + u1.y * c1;
        }
        if (i < e2) {
            int2 p = pairs[i];
            float c0 = dinv[p.x] * di;
            float2 u = *(const float2*)(xw + (size_t)p.x * CH + 2 * lane);
            ax += u.x * c0;
            ay += u.y * c0;
        }
        float2 bgv = *(const float2*)(bg + 2 * lane);
        float2 res = {ax + bgv.x, ay + bgv.y};
        *(float2*)(z1 + (size_t)c * CH + 2 * lane) = res;
    }
    grid.sync();  // S7

    // ---- P7: edge scoring, one wave per target node; z1[c] stays in registers ----
    for (int c = wid; c < NODES; c += GSIZE / 64) {
        float2 v = *(const float2*)(z1 + (size_t)c * CH + 2 * lane);
        float zc = z2v[c];
        int s = startArr[c], e2 = startArr[c + 1];
        int i = s;
        for (; i + 1 < e2; i += 2) {
            int2 p0 = pairs[i], p1 = pairs[i + 1];
            float2 u0 = *(const float2*)(z1 + (size_t)p0.x * CH + 2 * lane);
            float2 u1 = *(const float2*)(z1 + (size_t)p1.x * CH + 2 * lane);
            float d0 = v.x * u0.x + v.y * u0.y;
            float d1 = v.x * u1.x + v.y * u1.y;
#pragma unroll
            for (int off = 1; off < 64; off <<= 1) {
                d0 += __shfl_xor(d0, off, 64);
                d1 += __shfl_xor(d1, off, 64);
            }
            if (lane == 0) {
                float vn0 = zc + z2v[p0.x], vn1 = zc + z2v[p1.x];
                float sf0 = 1.f / (1.f + __expf(-d0)), sn0 = 1.f / (1.f + __expf(-vn0));
                float sf1 = 1.f / (1.f + __expf(-d1)), sn1 = 1.f / (1.f + __expf(-vn1));
                out[p0.y] = sf0 * sf0 + (1.f - sf0) * sn0;
                out[p1.y] = sf1 * sf1 + (1.f - sf1) * sn1;
            }
        }
        if (i < e2) {
            int2 p = pairs[i];
            float2 u = *(const float2*)(z1 + (size_t)p.x * CH + 2 * lane);
            float d = v.x * u.x + v.y * u.y;
#pragma unroll
            for (int off = 1; off < 64; off <<= 1) d += __shfl_xor(d, off, 64);
            if (lane == 0) {
                float vn = zc + z2v[p.x];
                float sfv = 1.f / (1.f + __expf(-d));
                float snv = 1.f / (1.f + __expf(-vn));
                out[p.y] = sfv * sfv + (1.f - sfv) * snv;
            }
        }
    }
}

extern "C" void kernel_launch(void* const* d_in, const int* in_sizes, int n_in,
                              void* d_out, int out_size, void* d_ws, size_t ws_size,
                              hipStream_t stream) {
    const float* x   = (const float*)d_in[0];
    const float* x2  = (const float*)d_in[1];
    const float* W2  = (const float*)d_in[2];
    const float* b2  = (const float*)d_in[3];
    const float* Wg  = (const float*)d_in[4];
    const float* bg  = (const float*)d_in[5];
    const float* W22 = (const float*)d_in[6];
    const int*   ei  = (const int*)d_in[7];
    float* out = (float*)d_out;

    char* ws = (char*)d_ws;
    size_t off = 0;
    auto alloc = [&](size_t bytes) -> void* {
        void* p = ws + off;
        off = (off + bytes + 255) & ~(size_t)255;
        return p;
    };
    int*   deg      = (int*)alloc(NODES * 4);
    int*   cursor   = (int*)alloc(NODES * 4);
    int*   startArr = (int*)alloc((NODES + 1) * 4);
    float* dinv     = (float*)alloc(NODES * 4);
    int2*  pairs    = (int2*)alloc((size_t)NEDGE * 8);
    int*   blockSum = (int*)alloc(NB * 4);
    float* h        = (float*)alloc((size_t)NODES * CH * 4);
    float* xw       = (float*)alloc((size_t)NODES * CH * 4);
    float* z1       = (float*)alloc((size_t)NODES * CH * 4);
    float* z2v      = (float*)alloc(NODES * 4);

    void* args[] = {&x, &x2, &W2, &b2, &Wg, &bg, &W22, &ei, &out,
                    &deg, &cursor, &startArr, &dinv, &pairs, &blockSum,
                    &h, &xw, &z1, &z2v};
    hipLaunchCooperativeKernel((const void*)fused, dim3(NB), dim3(NT), args, 0, stream);
}

// Round 3
// 692.709 us; speedup vs baseline: 1.6223x; 1.6223x over previous
//
#include <hip/hip_runtime.h>
#include <math.h>

#define NODES 10000
#define NEDGE 320000
#define INDIM 512
#define CH    128

typedef float f32x4 __attribute__((ext_vector_type(4)));
typedef short s16x8 __attribute__((ext_vector_type(8)));
typedef short s16x4 __attribute__((ext_vector_type(4)));

// bf16 round-to-nearest-even
__device__ __forceinline__ short f2bf(float f) {
    unsigned u = __float_as_uint(f);
    return (short)((u + 0x7fffu + ((u >> 16) & 1u)) >> 16);
}
__device__ __forceinline__ float bf2f(short s) {
    return __uint_as_float(((unsigned)(unsigned short)s) << 16);
}

// ---- split-bf16 MFMA GEMM tile: rows [row0, row0+64) x 128 cols, out = A@W^T (+bias)(opt l2n*1.8)
__device__ __forceinline__ void gemm_tile(const float* __restrict__ A, const float* __restrict__ W,
                                          const float* __restrict__ bias, float* __restrict__ outp,
                                          int M, int K, bool l2n, int row0,
                                          short* Ah, short* Al, short* Bh, short* Bl) {
    const int SROW = 72;
    int tid = threadIdx.x;
    int wave = tid >> 6, lane = tid & 63, quad = lane >> 4, l16 = lane & 15;

    f32x4 acc[8];
#pragma unroll
    for (int t = 0; t < 8; t++) acc[t] = (f32x4){0.f, 0.f, 0.f, 0.f};

    for (int kb = 0; kb < K; kb += 64) {
        __syncthreads();
#pragma unroll
        for (int i = 0; i < 4; i++) {  // A tile: 64 rows x 64 k
            int idx = tid + 256 * i;
            int j = idx & 15, r = idx >> 4;
            float4 v = {0.f, 0.f, 0.f, 0.f};
            int grow = row0 + r;
            if (grow < M) v = *(const float4*)(A + (size_t)grow * K + kb + 4 * j);
            float vv[4] = {v.x, v.y, v.z, v.w};
            s16x4 h4, l4;
#pragma unroll
            for (int q = 0; q < 4; q++) {
                short hs = f2bf(vv[q]);
                h4[q] = hs;
                l4[q] = f2bf(vv[q] - bf2f(hs));
            }
            *(s16x4*)&Ah[r * SROW + 4 * j] = h4;
            *(s16x4*)&Al[r * SROW + 4 * j] = l4;
        }
#pragma unroll
        for (int i = 0; i < 8; i++) {  // B tile: 128 n x 64 k
            int idx = tid + 256 * i;
            int j = idx & 15, n = idx >> 4;
            float4 v = *(const float4*)(W + (size_t)n * K + kb + 4 * j);
            float vv[4] = {v.x, v.y, v.z, v.w};
            s16x4 h4, l4;
#pragma unroll
            for (int q = 0; q < 4; q++) {
                short hs = f2bf(vv[q]);
                h4[q] = hs;
                l4[q] = f2bf(vv[q] - bf2f(hs));
            }
            *(s16x4*)&Bh[n * SROW + 4 * j] = h4;
            *(s16x4*)&Bl[n * SROW + 4 * j] = l4;
        }
        __syncthreads();

#pragma unroll
        for (int kk = 0; kk < 64; kk += 32) {
            int aoff = (wave * 16 + l16) * SROW + kk + quad * 8;
            s16x8 ah = *(const s16x8*)&Ah[aoff];
            s16x8 al = *(const s16x8*)&Al[aoff];
#pragma unroll
            for (int t = 0; t < 8; t++) {
                int boff = (t * 16 + l16) * SROW + kk + quad * 8;
                s16x8 bh = *(const s16x8*)&Bh[boff];
                s16x8 bl = *(const s16x8*)&Bl[boff];
                acc[t] = __builtin_amdgcn_mfma_f32_16x16x32_bf16(ah, bh, acc[t], 0, 0, 0);
                acc[t] = __builtin_amdgcn_mfma_f32_16x16x32_bf16(ah, bl, acc[t], 0, 0, 0);
                acc[t] = __builtin_amdgcn_mfma_f32_16x16x32_bf16(al, bh, acc[t], 0, 0, 0);
            }
        }
    }

    if (bias) {
#pragma unroll
        for (int t = 0; t < 8; t++) {
            float bv = bias[t * 16 + l16];
#pragma unroll
            for (int r = 0; r < 4; r++) acc[t][r] += bv;
        }
    }
    if (l2n) {
#pragma unroll
        for (int r = 0; r < 4; r++) {
            float ss = 0.f;
#pragma unroll
            for (int t = 0; t < 8; t++) ss += acc[t][r] * acc[t][r];
#pragma unroll
            for (int off = 1; off < 16; off <<= 1) ss += __shfl_xor(ss, off, 64);
            float scale = 1.8f / fmaxf(sqrtf(ss), 1e-12f);
#pragma unroll
            for (int t = 0; t < 8; t++) acc[t][r] *= scale;
        }
    }
#pragma unroll
    for (int r = 0; r < 4; r++) {
        int grow = row0 + wave * 16 + quad * 4 + r;
        if (grow < M)
#pragma unroll
            for (int t = 0; t < 8; t++)
                outp[(size_t)grow * CH + t * 16 + l16] = acc[t][r];
    }
}

// ---- small launches ----
__global__ __launch_bounds__(256) void k_init(int* deg, int* cursor) {
    int i = blockIdx.x * 256 + threadIdx.x;
    if (i < NODES) { deg[i] = 1; cursor[i] = 0; }
}

__global__ __launch_bounds__(256) void k_count(const int* __restrict__ ei, int* deg) {
    int e = blockIdx.x * 256 + threadIdx.x;
    if (e < NEDGE) atomicAdd(&deg[ei[NEDGE + e]], 1);
}

__global__ __launch_bounds__(1024) void k_scan(const int* __restrict__ deg,
                                               int* startArr, float* dinv) {
    __shared__ int s[1024];
    const int CHUNK = 10;
    int t = threadIdx.x;
    int i0 = t * CHUNK;
    int local = 0;
    for (int j = 0; j < CHUNK; j++) {
        int i = i0 + j;
        if (i < NODES) local += deg[i] - 1;
    }
    s[t] = local;
    __syncthreads();
    for (int off = 1; off < 1024; off <<= 1) {
        int v = (t >= off) ? s[t - off] : 0;
        __syncthreads();
        s[t] += v;
        __syncthreads();
    }
    int run = s[t] - local;
    for (int j = 0; j < CHUNK; j++) {
        int i = i0 + j;
        if (i < NODES) {
            startArr[i] = run;
            run += deg[i] - 1;
            dinv[i] = rsqrtf((float)deg[i]);
        }
    }
    if (t == 1023) startArr[NODES] = NEDGE;
}

// ---- mega launch: blocks [0,157) gemm1 | [157,470) CSR fill | [470,2970) z2 wave-per-row ----
#define GB1 157
#define FB  313
#define ZB  2500
__global__ __launch_bounds__(256) void k_mega(
    const float* __restrict__ x, const float* __restrict__ W2, const float* __restrict__ b2,
    const float* __restrict__ x2, const float* __restrict__ W22,
    const int* __restrict__ ei, const int* __restrict__ startArr,
    int* cursor, int2* pairs, float* __restrict__ h, float* __restrict__ z2v) {
    __shared__ __align__(16) char smem[55296];
    int b = blockIdx.x, tid = threadIdx.x;
    int lane = tid & 63, wv = tid >> 6;

    if (b < GB1) {
        gemm_tile(x, W2, b2, h, NODES, INDIM, true, b * 64,
                  (short*)smem, (short*)(smem + 9216), (short*)(smem + 18432), (short*)(smem + 36864));
    } else if (b < GB1 + FB) {
        for (int e = (b - GB1) * 256 + tid; e < NEDGE; e += FB * 256) {
            int c = ei[NEDGE + e], src = ei[e];
            int pos = atomicAdd(&cursor[c], 1);
            pairs[startArr[c] + pos] = make_int2(src, e);
        }
    } else {
        int row = (b - GB1 - FB) * 4 + wv;  // 10000 rows, one per wave
        const float4* xr = (const float4*)(x2 + (size_t)row * NODES);
        const float4* w0 = (const float4*)W22;
        const float4* w1 = (const float4*)(W22 + NODES);
        float s0 = 0.f, s1 = 0.f;
        int j = lane;
#pragma unroll 4
        for (int k = 0; k < 39; k++) {  // 39*64 = 2496 of 2500 float4
            float4 v = xr[j];
            float4 a = w0[j];
            float4 c = w1[j];
            s0 += v.x * a.x + v.y * a.y + v.z * a.z + v.w * a.w;
            s1 += v.x * c.x + v.y * c.y + v.z * c.z + v.w * c.w;
            j += 64;
        }
        if (lane < 4) {  // tail: float4 idx 2496..2499
            int jt = 2496 + lane;
            float4 v = xr[jt];
            float4 a = w0[jt];
            float4 c = w1[jt];
            s0 += v.x * a.x + v.y * a.y + v.z * a.z + v.w * a.w;
            s1 += v.x * c.x + v.y * c.y + v.z * c.z + v.w * c.w;
        }
#pragma unroll
        for (int off = 1; off < 64; off <<= 1) {
            s0 += __shfl_xor(s0, off, 64);
            s1 += __shfl_xor(s1, off, 64);
        }
        if (lane == 0) {
            float n = sqrtf(s0 * s0 + s1 * s1);
            z2v[row] = 0.8f * s0 / fmaxf(n, 1e-12f);
        }
    }
}

__global__ __launch_bounds__(256) void k_gemm2(const float* __restrict__ h,
                                               const float* __restrict__ Wg,
                                               float* __restrict__ xw) {
    __shared__ __align__(16) char smem[55296];
    gemm_tile(h, Wg, nullptr, xw, NODES, CH, false, blockIdx.x * 64,
              (short*)smem, (short*)(smem + 9216), (short*)(smem + 18432), (short*)(smem + 36864));
}

// ---- GCN aggregation: wave-per-node CSR pull ----
__global__ __launch_bounds__(256) void k_agg(const float* __restrict__ xw,
                                             const float* __restrict__ dinv,
                                             const int2* __restrict__ pairs,
                                             const int* __restrict__ startArr,
                                             const float* __restrict__ bg,
                                             float* __restrict__ z1) {
    int node = blockIdx.x * 4 + (threadIdx.x >> 6);
    int lane = threadIdx.x & 63;
    if (node >= NODES) return;
    float di = dinv[node];
    float2 v = *(const float2*)(xw + (size_t)node * CH + 2 * lane);
    float ax = v.x * di * di, ay = v.y * di * di;
    int s = startArr[node], e2 = startArr[node + 1];
    int i = s;
    for (; i + 1 < e2; i += 2) {
        int2 p0 = pairs[i], p1 = pairs[i + 1];
        float c0 = dinv[p0.x] * di, c1 = dinv[p1.x] * di;
        float2 u0 = *(const float2*)(xw + (size_t)p0.x * CH + 2 * lane);
        float2 u1 = *(const float2*)(xw + (size_t)p1.x * CH + 2 * lane);
        ax += u0.x * c0 + u1.x * c1;
        ay += u0.y * c0 + u1.y * c1;
    }
    if (i < e2) {
        int2 p = pairs[i];
        float c0 = dinv[p.x] * di;
        float2 u = *(const float2*)(xw + (size_t)p.x * CH + 2 * lane);
        ax += u.x * c0;
        ay += u.y * c0;
    }
    float2 bgv = *(const float2*)(bg + 2 * lane);
    float2 res = {ax + bgv.x, ay + bgv.y};
    *(float2*)(z1 + (size_t)node * CH + 2 * lane) = res;
}

// ---- edge scoring: wave-per-target-node, z1[c] in registers ----
__global__ __launch_bounds__(256) void k_score(const float* __restrict__ z1,
                                               const float* __restrict__ z2v,
                                               const int2* __restrict__ pairs,
                                               const int* __restrict__ startArr,
                                               float* __restrict__ out) {
    int c = blockIdx.x * 4 + (threadIdx.x >> 6);
    int lane = threadIdx.x & 63;
    if (c >= NODES) return;
    float2 v = *(const float2*)(z1 + (size_t)c * CH + 2 * lane);
    float zc = z2v[c];
    int s = startArr[c], e2 = startArr[c + 1];
    int i = s;
    for (; i + 1 < e2; i += 2) {
        int2 p0 = pairs[i], p1 = pairs[i + 1];
        float2 u0 = *(const float2*)(z1 + (size_t)p0.x * CH + 2 * lane);
        float2 u1 = *(const float2*)(z1 + (size_t)p1.x * CH + 2 * lane);
        float d0 = v.x * u0.x + v.y * u0.y;
        float d1 = v.x * u1.x + v.y * u1.y;
#pragma unroll
        for (int off = 1; off < 64; off <<= 1) {
            d0 += __shfl_xor(d0, off, 64);
            d1 += __shfl_xor(d1, off, 64);
        }
        if (lane == 0) {
            float vn0 = zc + z2v[p0.x], vn1 = zc + z2v[p1.x];
            float sf0 = 1.f / (1.f + __expf(-d0)), sn0 = 1.f / (1.f + __expf(-vn0));
            float sf1 = 1.f / (1.f + __expf(-d1)), sn1 = 1.f / (1.f + __expf(-vn1));
            out[p0.y] = sf0 * sf0 + (1.f - sf0) * sn0;
            out[p1.y] = sf1 * sf1 + (1.f - sf1) * sn1;
        }
    }
    if (i < e2) {
        int2 p = pairs[i];
        float2 u = *(const float2*)(z1 + (size_t)p.x * CH + 2 * lane);
        float d = v.x * u.x + v.y * u.y;
#pragma unroll
        for (int off = 1; off < 64; off <<= 1) d += __shfl_xor(d, off, 64);
        if (lane == 0) {
            float vn = zc + z2v[p.x];
            float sfv = 1.f / (1.f + __expf(-d));
            float snv = 1.f / (1.f + __expf(-vn));
            out[p.y] = sfv * sfv + (1.f - sfv) * snv;
        }
    }
}

extern "C" void kernel_launch(void* const* d_in, const int* in_sizes, int n_in,
                              void* d_out, int out_size, void* d_ws, size_t ws_size,
                              hipStream_t stream) {
    const float* x   = (const float*)d_in[0];
    const float* x2  = (const float*)d_in[1];
    const float* W2  = (const float*)d_in[2];
    const float* b2  = (const float*)d_in[3];
    const float* Wg  = (const float*)d_in[4];
    const float* bg  = (const float*)d_in[5];
    const float* W22 = (const float*)d_in[6];
    const int*   ei  = (const int*)d_in[7];
    float* out = (float*)d_out;

    char* ws = (char*)d_ws;
    size_t off = 0;
    auto alloc = [&](size_t bytes) -> void* {
        void* p = ws + off;
        off = (off + bytes + 255) & ~(size_t)255;
        return p;
    };
    int*   deg      = (int*)alloc(NODES * 4);
    int*   cursor   = (int*)alloc(NODES * 4);
    int*   startArr = (int*)alloc((NODES + 1) * 4);
    float* dinv     = (float*)alloc(NODES * 4);
    int2*  pairs    = (int2*)alloc((size_t)NEDGE * 8);
    float* h        = (float*)alloc((size_t)NODES * CH * 4);
    float* xw       = (float*)alloc((size_t)NODES * CH * 4);
    float* z1       = (float*)alloc((size_t)NODES * CH * 4);
    float* z2v      = (float*)alloc(NODES * 4);

    k_init<<<(NODES + 255) / 256, 256, 0, stream>>>(deg, cursor);
    k_count<<<(NEDGE + 255) / 256, 256, 0, stream>>>(ei, deg);
    k_scan<<<1, 1024, 0, stream>>>(deg, startArr, dinv);
    k_mega<<<GB1 + FB + ZB, 256, 0, stream>>>(x, W2, b2, x2, W22, ei, startArr,
                                              cursor, pairs, h, z2v);
    k_gemm2<<<GB1, 256, 0, stream>>>(h, Wg, xw);
    k_agg<<<(NODES + 3) / 4, 256, 0, stream>>>(xw, dinv, pairs, startArr, bg, z1);
    k_score<<<(NODES + 3) / 4, 256, 0, stream>>>(z1, z2v, pairs, startArr, out);
}